// Round 3
// baseline (707.827 us; speedup 1.0000x reference)
//
#include <hip/hip_runtime.h>
#include <stdint.h>

// Fully-fused MLP: 1048576 x (64 -> 128 -> 128 -> 128 -> 128 -> 64)
// ReLU after all but last layer. fp32 in/out, bf16 MFMA compute (fp32 accum).
//
// Persistent blocks + all weights in LDS (r2, verified) with two new levers:
//  - 1024-thread blocks (16 waves): weights-in-LDS forces 1 block/CU, so a
//    bigger block is the only occupancy lever. 4 waves/SIMD instead of 2;
//    total LDS/MFMA/HBM work per CU unchanged (16 waves x 4 chunks).
//  - layer-0 mt-outer: convert prefetched x into 8 B-frags once (bx[4][2]),
//    then read each L0 A-frag/bias exactly once (16+8 ds_reads vs 64+32).
//  - x prefetch split in halves (nt0-1 before out-layer, nt2-3 after) to keep
//    the out-layer live set at ba(64)+32 and stay under the 128-VGPR cap.
// Chunk loop remains barrier-free: waves drift and self-stagger.

#define D_IN   64
#define D_HID  128
#define D_OUT  64
#define N_HID  3
#define NT     4                     // 16-row tiles per wave per chunk
#define WAVES  16
#define BLOCK  (WAVES * 64)          // 1024
#define GRID   256
#define ITERS  4                     // 256 blocks * 1024 rows * 4 = 1048576
#define ROWS_PER_WAVE (NT * 16)      // 64
#define ROWS_PER_BLOCK (WAVES * ROWS_PER_WAVE)  // 1024

// ---- LDS layout (ushort element offsets) ----
// L0:  16 slots (mt*2+s),  [0, 8192)
// H l: 32 slots (mt*4+s),  [8192 + l*16384, ...)   l = 0..2
// OUT: 16 slots (mt*4+s),  [57344, 65536)
// biases (f32) after weights: 128 + 384 + 64 = 576 floats
#define L0_OFF   0
#define H_OFF    8192
#define H_STRIDE 16384
#define OUT_OFF  57344
#define W_ELEMS  65536
#define LDS_BYTES (W_ELEMS * 2 + 576 * 4)   // 133376

typedef __attribute__((ext_vector_type(8))) short  short8;   // 8 x bf16
typedef __attribute__((ext_vector_type(4))) float  floatx4;

union U4 { short8 s8; unsigned int u[4]; };

__device__ __forceinline__ unsigned int bfround(unsigned int u) {
  return u + 0x7fffu + ((u >> 16) & 1u);
}
__device__ __forceinline__ unsigned int cvt_pk_bf16(float lo, float hi) {
  unsigned int r;
  asm("v_cvt_pk_bf16_f32 %0, %1, %2" : "=v"(r) : "v"(lo), "v"(hi));
  return r;
}
__device__ __forceinline__ floatx4 mfma16(short8 a, short8 b, floatx4 c) {
  return __builtin_amdgcn_mfma_f32_16x16x32_bf16(a, b, c, 0, 0, 0);
}
__device__ __forceinline__ short8 ldsfrag(const unsigned short* p) {
  short8 v;
  __builtin_memcpy(&v, __builtin_assume_aligned(p, 16), 16);
  return v;
}
__device__ __forceinline__ floatx4 ldsbias(const float* p) {
  floatx4 v;
  __builtin_memcpy(&v, __builtin_assume_aligned(p, 16), 16);
  return v;
}

// ---- weight pre-arrangement -------------------------------------------------
#define W_IN_ELEMS  (D_HID * D_IN)
#define W_HID_ELEMS (N_HID * D_HID * D_HID)
#define W_OUT_ELEMS (D_OUT * D_HID)

// stored contraction position kp -> source input-feature index (verified r1)
__device__ __forceinline__ int kperm(int kp) {
  return 32 * (kp >> 5) + 16 * ((kp >> 2) & 1) + 4 * ((kp >> 3) & 3) + (kp & 3);
}

// arranged bf16 image: elem = region_off + slot*512 + lane*8 + j
// lane fields: c = lane&15 (A row within mtile), q = lane>>4 (k chunk)
__global__ void wconvert_kernel(const float* __restrict__ w_in,
                                const float* __restrict__ w_hid,
                                const float* __restrict__ w_out,
                                unsigned short* __restrict__ wbf) {
  const int i = blockIdx.x * 256 + threadIdx.x;
  float v;
  if (i < H_OFF) {
    // layer 0: natural k (B comes from x). slot = mt*2+s
    const int mt = i >> 10;
    const int r  = i & 1023;
    const int s  = r >> 9;
    const int l  = (r >> 3) & 63;
    const int j  = r & 7;
    const int c = l & 15, q = l >> 4;
    v = w_in[(mt * 16 + c) * D_IN + s * 32 + q * 8 + j];
  } else if (i < OUT_OFF) {
    // hidden layer lh: permuted k. slot = mt*4+s
    const int ii = i - H_OFF;
    const int lh = ii >> 14;
    const int r0 = ii & 16383;
    const int mt = r0 >> 11;
    const int r  = r0 & 2047;
    const int s  = r >> 9;
    const int l  = (r >> 3) & 63;
    const int j  = r & 7;
    const int c = l & 15, q = l >> 4;
    v = w_hid[lh * (D_HID * D_HID) + (mt * 16 + c) * D_HID + kperm(s * 32 + q * 8 + j)];
  } else {
    // out layer: permuted k. slot = mt*4+s
    const int ii = i - OUT_OFF;
    const int mt = ii >> 11;
    const int r  = ii & 2047;
    const int s  = r >> 9;
    const int l  = (r >> 3) & 63;
    const int j  = r & 7;
    const int c = l & 15, q = l >> 4;
    v = w_out[(mt * 16 + c) * D_HID + kperm(s * 32 + q * 8 + j)];
  }
  wbf[i] = (unsigned short)(bfround(__float_as_uint(v)) >> 16);
}

// ---- hidden layer: K=128 (4 ksteps), M=128 (8 mtiles), ReLU, in-lane D->B --
__device__ __forceinline__ void hidden_layer(const U4 (&bin)[NT][4], U4 (&bout)[NT][4],
                                             const unsigned short* __restrict__ fb,
                                             const float* __restrict__ blds,
                                             int lh, int q) {
  const unsigned short* wl = fb + H_OFF + lh * H_STRIDE;
  const float* bl = blds + 128 + lh * 128;
#pragma unroll
  for (int mt = 0; mt < 8; ++mt) {
    short8 a0 = ldsfrag(wl + (mt * 4 + 0) * 512);
    short8 a1 = ldsfrag(wl + (mt * 4 + 1) * 512);
    short8 a2 = ldsfrag(wl + (mt * 4 + 2) * 512);
    short8 a3 = ldsfrag(wl + (mt * 4 + 3) * 512);
    floatx4 bias = ldsbias(bl + mt * 16 + q * 4);
#pragma unroll
    for (int nt = 0; nt < NT; ++nt) {
      floatx4 acc = bias;
      acc = mfma16(a0, bin[nt][0].s8, acc);
      acc = mfma16(a1, bin[nt][1].s8, acc);
      acc = mfma16(a2, bin[nt][2].s8, acc);
      acc = mfma16(a3, bin[nt][3].s8, acc);
      bout[nt][mt >> 1].u[2 * (mt & 1) + 0] =
          cvt_pk_bf16(fmaxf(acc[0], 0.f), fmaxf(acc[1], 0.f));
      bout[nt][mt >> 1].u[2 * (mt & 1) + 1] =
          cvt_pk_bf16(fmaxf(acc[2], 0.f), fmaxf(acc[3], 0.f));
    }
  }
}

// ---- main fused kernel ------------------------------------------------------
__global__ __launch_bounds__(BLOCK, 4) void mlp_kernel(
    const float* __restrict__ x,
    const unsigned short* __restrict__ wbf,
    const float* __restrict__ b_in,
    const float* __restrict__ b_hid,
    const float* __restrict__ b_out,
    float* __restrict__ out) {
  extern __shared__ unsigned short wlds[];
  const int tid  = threadIdx.x;
  const int wv   = tid >> 6;
  const int lane = tid & 63;
  const int q    = lane >> 4;
  const int c    = lane & 15;

  // ---- one-time stage: 128KB weights + 2.25KB biases into LDS ----
  {
    uint4* dst = (uint4*)wlds;
    const uint4* src = (const uint4*)wbf;
#pragma unroll
    for (int i = 0; i < 8; ++i) dst[tid + i * BLOCK] = src[tid + i * BLOCK];
    float* bl = (float*)(wlds + W_ELEMS);
    if (tid < 128) bl[tid] = b_in[tid];
    if (tid < 384) bl[128 + tid] = b_hid[tid];
    if (tid < 64)  bl[512 + tid] = b_out[tid];
  }
  __syncthreads();
  // weights read-only from here on: NO further barriers, waves drift freely.

  const unsigned short* fb = wlds + lane * 8;   // lane-linear frag base
  const float* blds = (const float*)(wlds + W_ELEMS);

  U4 ba[NT][4], bb[NT][4];
  floatx4 p1[8], p2[8];   // x prefetch halves: nt0-1 / nt2-3 (32 VGPR each)

  // prologue: both halves for chunk 0
  {
    const int rb = blockIdx.x * ROWS_PER_BLOCK + wv * ROWS_PER_WAVE;
#pragma unroll
    for (int h = 0; h < 2; ++h) {
      const float* xr = x + (rb + h * 16 + c) * D_IN + q * 8;
      p1[h * 4 + 0] = *(const floatx4*)(xr);
      p1[h * 4 + 1] = *(const floatx4*)(xr + 4);
      p1[h * 4 + 2] = *(const floatx4*)(xr + 32);
      p1[h * 4 + 3] = *(const floatx4*)(xr + 36);
    }
#pragma unroll
    for (int h = 0; h < 2; ++h) {
      const float* xr = x + (rb + (h + 2) * 16 + c) * D_IN + q * 8;
      p2[h * 4 + 0] = *(const floatx4*)(xr);
      p2[h * 4 + 1] = *(const floatx4*)(xr + 4);
      p2[h * 4 + 2] = *(const floatx4*)(xr + 32);
      p2[h * 4 + 3] = *(const floatx4*)(xr + 36);
    }
  }

#pragma unroll 1
  for (int it = 0; it < ITERS; ++it) {
    const int rb = (it * GRID + blockIdx.x) * ROWS_PER_BLOCK + wv * ROWS_PER_WAVE;

    // ---- layer 0: convert prefetch -> 8 B-frags, then mt-outer (K=64) ----
    U4 bx[NT][2];
#pragma unroll
    for (int h = 0; h < 2; ++h) {
      bx[h][0].u[0] = cvt_pk_bf16(p1[h * 4 + 0][0], p1[h * 4 + 0][1]);
      bx[h][0].u[1] = cvt_pk_bf16(p1[h * 4 + 0][2], p1[h * 4 + 0][3]);
      bx[h][0].u[2] = cvt_pk_bf16(p1[h * 4 + 1][0], p1[h * 4 + 1][1]);
      bx[h][0].u[3] = cvt_pk_bf16(p1[h * 4 + 1][2], p1[h * 4 + 1][3]);
      bx[h][1].u[0] = cvt_pk_bf16(p1[h * 4 + 2][0], p1[h * 4 + 2][1]);
      bx[h][1].u[1] = cvt_pk_bf16(p1[h * 4 + 2][2], p1[h * 4 + 2][3]);
      bx[h][1].u[2] = cvt_pk_bf16(p1[h * 4 + 3][0], p1[h * 4 + 3][1]);
      bx[h][1].u[3] = cvt_pk_bf16(p1[h * 4 + 3][2], p1[h * 4 + 3][3]);
      bx[h + 2][0].u[0] = cvt_pk_bf16(p2[h * 4 + 0][0], p2[h * 4 + 0][1]);
      bx[h + 2][0].u[1] = cvt_pk_bf16(p2[h * 4 + 0][2], p2[h * 4 + 0][3]);
      bx[h + 2][0].u[2] = cvt_pk_bf16(p2[h * 4 + 1][0], p2[h * 4 + 1][1]);
      bx[h + 2][0].u[3] = cvt_pk_bf16(p2[h * 4 + 1][2], p2[h * 4 + 1][3]);
      bx[h + 2][1].u[0] = cvt_pk_bf16(p2[h * 4 + 2][0], p2[h * 4 + 2][1]);
      bx[h + 2][1].u[1] = cvt_pk_bf16(p2[h * 4 + 2][2], p2[h * 4 + 2][3]);
      bx[h + 2][1].u[2] = cvt_pk_bf16(p2[h * 4 + 3][0], p2[h * 4 + 3][1]);
      bx[h + 2][1].u[3] = cvt_pk_bf16(p2[h * 4 + 3][2], p2[h * 4 + 3][3]);
    }
#pragma unroll
    for (int mt = 0; mt < 8; ++mt) {
      short8 a0 = ldsfrag(fb + L0_OFF + (mt * 2 + 0) * 512);
      short8 a1 = ldsfrag(fb + L0_OFF + (mt * 2 + 1) * 512);
      floatx4 bias = ldsbias(blds + mt * 16 + q * 4);
#pragma unroll
      for (int nt = 0; nt < NT; ++nt) {
        floatx4 acc = bias;
        acc = mfma16(a0, bx[nt][0].s8, acc);
        acc = mfma16(a1, bx[nt][1].s8, acc);
        bb[nt][mt >> 1].u[2 * (mt & 1) + 0] =
            cvt_pk_bf16(fmaxf(acc[0], 0.f), fmaxf(acc[1], 0.f));
        bb[nt][mt >> 1].u[2 * (mt & 1) + 1] =
            cvt_pk_bf16(fmaxf(acc[2], 0.f), fmaxf(acc[3], 0.f));
      }
    }

    // ---- hidden layers: ping-pong bb -> ba -> bb -> ba ----
    hidden_layer(bb, ba, fb, blds, 0, q);
    hidden_layer(ba, bb, fb, blds, 1, q);
    hidden_layer(bb, ba, fb, blds, 2, q);

    // ---- prefetch half 1 of next chunk's x (covered by out-layer) ----
    if (it + 1 < ITERS) {
      const int nrb = ((it + 1) * GRID + blockIdx.x) * ROWS_PER_BLOCK + wv * ROWS_PER_WAVE;
#pragma unroll
      for (int h = 0; h < 2; ++h) {
        const float* xr = x + (nrb + h * 16 + c) * D_IN + q * 8;
        p1[h * 4 + 0] = *(const floatx4*)(xr);
        p1[h * 4 + 1] = *(const floatx4*)(xr + 4);
        p1[h * 4 + 2] = *(const floatx4*)(xr + 32);
        p1[h * 4 + 3] = *(const floatx4*)(xr + 36);
      }
    }

    // ---- output layer: M=64 (4 mtiles), K=128, no activation ----
#pragma unroll
    for (int mt = 0; mt < 4; ++mt) {
      short8 a0 = ldsfrag(fb + OUT_OFF + (mt * 4 + 0) * 512);
      short8 a1 = ldsfrag(fb + OUT_OFF + (mt * 4 + 1) * 512);
      short8 a2 = ldsfrag(fb + OUT_OFF + (mt * 4 + 2) * 512);
      short8 a3 = ldsfrag(fb + OUT_OFF + (mt * 4 + 3) * 512);
      floatx4 bias = ldsbias(blds + 512 + mt * 16 + q * 4);
#pragma unroll
      for (int nt = 0; nt < NT; ++nt) {
        floatx4 acc = bias;
        acc = mfma16(a0, ba[nt][0].s8, acc);
        acc = mfma16(a1, ba[nt][1].s8, acc);
        acc = mfma16(a2, ba[nt][2].s8, acc);
        acc = mfma16(a3, ba[nt][3].s8, acc);
        *(floatx4*)(out + (rb + nt * 16 + c) * D_OUT + mt * 16 + q * 4) = acc;
      }
    }

    // ---- prefetch half 2 of next chunk's x (after out-layer stores) ----
    if (it + 1 < ITERS) {
      const int nrb = ((it + 1) * GRID + blockIdx.x) * ROWS_PER_BLOCK + wv * ROWS_PER_WAVE;
#pragma unroll
      for (int h = 0; h < 2; ++h) {
        const float* xr = x + (nrb + (h + 2) * 16 + c) * D_IN + q * 8;
        p2[h * 4 + 0] = *(const floatx4*)(xr);
        p2[h * 4 + 1] = *(const floatx4*)(xr + 4);
        p2[h * 4 + 2] = *(const floatx4*)(xr + 32);
        p2[h * 4 + 3] = *(const floatx4*)(xr + 36);
      }
    }
  }
}

extern "C" void kernel_launch(void* const* d_in, const int* in_sizes, int n_in,
                              void* d_out, int out_size, void* d_ws, size_t ws_size,
                              hipStream_t stream) {
  const float* x     = (const float*)d_in[0];
  const float* w_in  = (const float*)d_in[1];
  const float* b_in  = (const float*)d_in[2];
  const float* w_hid = (const float*)d_in[3];
  const float* b_hid = (const float*)d_in[4];
  const float* w_out = (const float*)d_in[5];
  const float* b_out = (const float*)d_in[6];
  float* out = (float*)d_out;
  unsigned short* wbf = (unsigned short*)d_ws;  // 131072 bytes used

  // arrange weights fp32 -> bf16 frag-linear image (re-done every launch)
  wconvert_kernel<<<W_ELEMS / 256, 256, 0, stream>>>(w_in, w_hid, w_out, wbf);

  // allow >64KB dynamic LDS (gfx950 has 160KB/CU)
  (void)hipFuncSetAttribute((const void*)mlp_kernel,
                            hipFuncAttributeMaxDynamicSharedMemorySize, LDS_BYTES);

  mlp_kernel<<<GRID, BLOCK, LDS_BYTES, stream>>>(x, wbf, b_in, b_hid, b_out, out);
}

// Round 4
// 566.860 us; speedup vs baseline: 1.2487x; 1.2487x over previous
//
#include <hip/hip_runtime.h>
#include <stdint.h>

// Fully-fused MLP: 1048576 x (64 -> 128 -> 128 -> 128 -> 128 -> 64)
// ReLU after all but last layer. fp32 in/out, bf16 MFMA compute (fp32 accum).
//
// r4 = r2 structure (persistent blocks, all weights in LDS, in-lane D->B via
// weight k-permutation, barrier-free chunk loop) with occupancy 2->3 waves/SIMD:
//  - 12-wave (768-thread) blocks, 1 block/CU (LDS 133KB). 3 waves/SIMD needs
//    VGPR <= 170; NT=4 live set peaks ~155. Allocation PINNED with
//    amdgpu_waves_per_eu(3,3) so the allocator cannot target higher occupancy
//    and spill (r3 failure: it went to 64 VGPR / 1GB scratch traffic).
//  - 256 blocks x 4096 contiguous rows; 64 chunks of 64 rows round-robin over
//    12 waves (waves 0-3: 6 chunks, 4-11: 5). Waves 0-3 sit on distinct SIMDs
//    -> each SIMD carries exactly 16 chunks: per-SIMD balanced.
//  - x prefetch for chunk ck+12 issued just before the out-layer (bb dead),
//    converted to B-frags at the next chunk's layer-0 (px dies there).

#define D_IN   64
#define D_HID  128
#define D_OUT  64
#define N_HID  3
#define NT     4                     // 16-row tiles per wave per chunk
#define WAVES  12
#define BLOCK  (WAVES * 64)          // 768
#define GRID   256
#define CHUNKS 64                    // 64-row chunks per block (64*64 = 4096 rows)
#define ROWS_PER_BLOCK 4096          // GRID * 4096 = 1048576

// ---- LDS layout (ushort element offsets) ----
// L0:  16 slots (mt*2+s),  [0, 8192)
// H l: 32 slots (mt*4+s),  [8192 + l*16384, ...)   l = 0..2
// OUT: 16 slots (mt*4+s),  [57344, 65536)
// biases (f32) after weights: 128 + 384 + 64 = 576 floats
#define L0_OFF   0
#define H_OFF    8192
#define H_STRIDE 16384
#define OUT_OFF  57344
#define W_ELEMS  65536
#define LDS_BYTES (W_ELEMS * 2 + 576 * 4)   // 133376

typedef __attribute__((ext_vector_type(8))) short  short8;   // 8 x bf16
typedef __attribute__((ext_vector_type(4))) float  floatx4;

union U4 { short8 s8; unsigned int u[4]; };

__device__ __forceinline__ unsigned int bfround(unsigned int u) {
  return u + 0x7fffu + ((u >> 16) & 1u);
}
__device__ __forceinline__ unsigned int cvt_pk_bf16(float lo, float hi) {
  unsigned int r;
  asm("v_cvt_pk_bf16_f32 %0, %1, %2" : "=v"(r) : "v"(lo), "v"(hi));
  return r;
}
__device__ __forceinline__ floatx4 mfma16(short8 a, short8 b, floatx4 c) {
  return __builtin_amdgcn_mfma_f32_16x16x32_bf16(a, b, c, 0, 0, 0);
}
__device__ __forceinline__ short8 ldsfrag(const unsigned short* p) {
  short8 v;
  __builtin_memcpy(&v, __builtin_assume_aligned(p, 16), 16);
  return v;
}
__device__ __forceinline__ floatx4 ldsbias(const float* p) {
  floatx4 v;
  __builtin_memcpy(&v, __builtin_assume_aligned(p, 16), 16);
  return v;
}

// ---- weight pre-arrangement -------------------------------------------------
#define W_IN_ELEMS  (D_HID * D_IN)
#define W_HID_ELEMS (N_HID * D_HID * D_HID)
#define W_OUT_ELEMS (D_OUT * D_HID)

// stored contraction position kp -> source input-feature index (verified r1)
__device__ __forceinline__ int kperm(int kp) {
  return 32 * (kp >> 5) + 16 * ((kp >> 2) & 1) + 4 * ((kp >> 3) & 3) + (kp & 3);
}

// arranged bf16 image: elem = region_off + slot*512 + lane*8 + j
// lane fields: c = lane&15 (A row within mtile), q = lane>>4 (k chunk)
__global__ void wconvert_kernel(const float* __restrict__ w_in,
                                const float* __restrict__ w_hid,
                                const float* __restrict__ w_out,
                                unsigned short* __restrict__ wbf) {
  const int i = blockIdx.x * 256 + threadIdx.x;
  float v;
  if (i < H_OFF) {
    // layer 0: natural k (B comes from x). slot = mt*2+s
    const int mt = i >> 10;
    const int r  = i & 1023;
    const int s  = r >> 9;
    const int l  = (r >> 3) & 63;
    const int j  = r & 7;
    const int c = l & 15, q = l >> 4;
    v = w_in[(mt * 16 + c) * D_IN + s * 32 + q * 8 + j];
  } else if (i < OUT_OFF) {
    // hidden layer lh: permuted k. slot = mt*4+s
    const int ii = i - H_OFF;
    const int lh = ii >> 14;
    const int r0 = ii & 16383;
    const int mt = r0 >> 11;
    const int r  = r0 & 2047;
    const int s  = r >> 9;
    const int l  = (r >> 3) & 63;
    const int j  = r & 7;
    const int c = l & 15, q = l >> 4;
    v = w_hid[lh * (D_HID * D_HID) + (mt * 16 + c) * D_HID + kperm(s * 32 + q * 8 + j)];
  } else {
    // out layer: permuted k. slot = mt*4+s
    const int ii = i - OUT_OFF;
    const int mt = ii >> 11;
    const int r  = ii & 2047;
    const int s  = r >> 9;
    const int l  = (r >> 3) & 63;
    const int j  = r & 7;
    const int c = l & 15, q = l >> 4;
    v = w_out[(mt * 16 + c) * D_HID + kperm(s * 32 + q * 8 + j)];
  }
  wbf[i] = (unsigned short)(bfround(__float_as_uint(v)) >> 16);
}

// ---- hidden layer: K=128 (4 ksteps), M=128 (8 mtiles), ReLU, in-lane D->B --
__device__ __forceinline__ void hidden_layer(const U4 (&bin)[NT][4], U4 (&bout)[NT][4],
                                             const unsigned short* __restrict__ fb,
                                             const float* __restrict__ blds,
                                             int lh, int q) {
  const unsigned short* wl = fb + H_OFF + lh * H_STRIDE;
  const float* bl = blds + 128 + lh * 128;
#pragma unroll
  for (int mt = 0; mt < 8; ++mt) {
    short8 a0 = ldsfrag(wl + (mt * 4 + 0) * 512);
    short8 a1 = ldsfrag(wl + (mt * 4 + 1) * 512);
    short8 a2 = ldsfrag(wl + (mt * 4 + 2) * 512);
    short8 a3 = ldsfrag(wl + (mt * 4 + 3) * 512);
    floatx4 bias = ldsbias(bl + mt * 16 + q * 4);
#pragma unroll
    for (int nt = 0; nt < NT; ++nt) {
      floatx4 acc = bias;
      acc = mfma16(a0, bin[nt][0].s8, acc);
      acc = mfma16(a1, bin[nt][1].s8, acc);
      acc = mfma16(a2, bin[nt][2].s8, acc);
      acc = mfma16(a3, bin[nt][3].s8, acc);
      bout[nt][mt >> 1].u[2 * (mt & 1) + 0] =
          cvt_pk_bf16(fmaxf(acc[0], 0.f), fmaxf(acc[1], 0.f));
      bout[nt][mt >> 1].u[2 * (mt & 1) + 1] =
          cvt_pk_bf16(fmaxf(acc[2], 0.f), fmaxf(acc[3], 0.f));
    }
  }
}

// ---- main fused kernel ------------------------------------------------------
__global__ __launch_bounds__(BLOCK)
__attribute__((amdgpu_waves_per_eu(3, 3)))
void mlp_kernel(
    const float* __restrict__ x,
    const unsigned short* __restrict__ wbf,
    const float* __restrict__ b_in,
    const float* __restrict__ b_hid,
    const float* __restrict__ b_out,
    float* __restrict__ out) {
  extern __shared__ unsigned short wlds[];
  const int tid  = threadIdx.x;
  const int wv   = tid >> 6;
  const int lane = tid & 63;
  const int q    = lane >> 4;
  const int c    = lane & 15;

  // ---- one-time stage: 128KB weights + 2.25KB biases into LDS ----
  {
    uint4* dst = (uint4*)wlds;
    const uint4* src = (const uint4*)wbf;
#pragma unroll
    for (int i = 0; i < 11; ++i) {
      const int idx = tid + i * BLOCK;
      if (idx < W_ELEMS / 8) dst[idx] = src[idx];
    }
    float* bl = (float*)(wlds + W_ELEMS);
    if (tid < 128) bl[tid] = b_in[tid];
    if (tid < 384) bl[128 + tid] = b_hid[tid];
    if (tid < 64)  bl[512 + tid] = b_out[tid];
  }
  __syncthreads();
  // weights read-only from here on: NO further barriers, waves drift freely.

  const unsigned short* fb = wlds + lane * 8;   // lane-linear frag base
  const float* blds = (const float*)(wlds + W_ELEMS);

  U4 ba[NT][4], bb[NT][4];
  floatx4 px[16];   // x prefetch: NT rows x 4 float4 (64 VGPR, live OUT->L0 only)

  const int blockrow = blockIdx.x * ROWS_PER_BLOCK;

  // prologue: load x for this wave's first chunk
  {
    const int rb = blockrow + wv * 64;
#pragma unroll
    for (int nt = 0; nt < NT; ++nt) {
      const float* xr = x + (rb + nt * 16 + c) * D_IN + q * 8;
      px[nt * 4 + 0] = *(const floatx4*)(xr);
      px[nt * 4 + 1] = *(const floatx4*)(xr + 4);
      px[nt * 4 + 2] = *(const floatx4*)(xr + 32);
      px[nt * 4 + 3] = *(const floatx4*)(xr + 36);
    }
  }

#pragma unroll 1
  for (int ck = wv; ck < CHUNKS; ck += WAVES) {
    const int rb = blockrow + ck * 64;

    // ---- layer 0: convert prefetch -> 8 B-frags (px dies), mt-outer, K=64 ----
    U4 bx[NT][2];
#pragma unroll
    for (int nt = 0; nt < NT; ++nt) {
      bx[nt][0].u[0] = cvt_pk_bf16(px[nt * 4 + 0][0], px[nt * 4 + 0][1]);
      bx[nt][0].u[1] = cvt_pk_bf16(px[nt * 4 + 0][2], px[nt * 4 + 0][3]);
      bx[nt][0].u[2] = cvt_pk_bf16(px[nt * 4 + 1][0], px[nt * 4 + 1][1]);
      bx[nt][0].u[3] = cvt_pk_bf16(px[nt * 4 + 1][2], px[nt * 4 + 1][3]);
      bx[nt][1].u[0] = cvt_pk_bf16(px[nt * 4 + 2][0], px[nt * 4 + 2][1]);
      bx[nt][1].u[1] = cvt_pk_bf16(px[nt * 4 + 2][2], px[nt * 4 + 2][3]);
      bx[nt][1].u[2] = cvt_pk_bf16(px[nt * 4 + 3][0], px[nt * 4 + 3][1]);
      bx[nt][1].u[3] = cvt_pk_bf16(px[nt * 4 + 3][2], px[nt * 4 + 3][3]);
    }
#pragma unroll
    for (int mt = 0; mt < 8; ++mt) {
      short8 a0 = ldsfrag(fb + L0_OFF + (mt * 2 + 0) * 512);
      short8 a1 = ldsfrag(fb + L0_OFF + (mt * 2 + 1) * 512);
      floatx4 bias = ldsbias(blds + mt * 16 + q * 4);
#pragma unroll
      for (int nt = 0; nt < NT; ++nt) {
        floatx4 acc = bias;
        acc = mfma16(a0, bx[nt][0].s8, acc);
        acc = mfma16(a1, bx[nt][1].s8, acc);
        bb[nt][mt >> 1].u[2 * (mt & 1) + 0] =
            cvt_pk_bf16(fmaxf(acc[0], 0.f), fmaxf(acc[1], 0.f));
        bb[nt][mt >> 1].u[2 * (mt & 1) + 1] =
            cvt_pk_bf16(fmaxf(acc[2], 0.f), fmaxf(acc[3], 0.f));
      }
    }

    // ---- hidden layers: ping-pong bb -> ba -> bb -> ba ----
    hidden_layer(bb, ba, fb, blds, 0, q);
    hidden_layer(ba, bb, fb, blds, 1, q);
    hidden_layer(bb, ba, fb, blds, 2, q);

    // ---- prefetch next chunk's x (bb dead; covered by out-layer compute) ----
    if (ck + WAVES < CHUNKS) {
      const int nrb = blockrow + (ck + WAVES) * 64;
#pragma unroll
      for (int nt = 0; nt < NT; ++nt) {
        const float* xr = x + (nrb + nt * 16 + c) * D_IN + q * 8;
        px[nt * 4 + 0] = *(const floatx4*)(xr);
        px[nt * 4 + 1] = *(const floatx4*)(xr + 4);
        px[nt * 4 + 2] = *(const floatx4*)(xr + 32);
        px[nt * 4 + 3] = *(const floatx4*)(xr + 36);
      }
    }

    // ---- output layer: M=64 (4 mtiles), K=128, no activation ----
#pragma unroll
    for (int mt = 0; mt < 4; ++mt) {
      short8 a0 = ldsfrag(fb + OUT_OFF + (mt * 4 + 0) * 512);
      short8 a1 = ldsfrag(fb + OUT_OFF + (mt * 4 + 1) * 512);
      short8 a2 = ldsfrag(fb + OUT_OFF + (mt * 4 + 2) * 512);
      short8 a3 = ldsfrag(fb + OUT_OFF + (mt * 4 + 3) * 512);
      floatx4 bias = ldsbias(blds + 512 + mt * 16 + q * 4);
#pragma unroll
      for (int nt = 0; nt < NT; ++nt) {
        floatx4 acc = bias;
        acc = mfma16(a0, ba[nt][0].s8, acc);
        acc = mfma16(a1, ba[nt][1].s8, acc);
        acc = mfma16(a2, ba[nt][2].s8, acc);
        acc = mfma16(a3, ba[nt][3].s8, acc);
        *(floatx4*)(out + (rb + nt * 16 + c) * D_OUT + mt * 16 + q * 4) = acc;
      }
    }
  }
}

extern "C" void kernel_launch(void* const* d_in, const int* in_sizes, int n_in,
                              void* d_out, int out_size, void* d_ws, size_t ws_size,
                              hipStream_t stream) {
  const float* x     = (const float*)d_in[0];
  const float* w_in  = (const float*)d_in[1];
  const float* b_in  = (const float*)d_in[2];
  const float* w_hid = (const float*)d_in[3];
  const float* b_hid = (const float*)d_in[4];
  const float* w_out = (const float*)d_in[5];
  const float* b_out = (const float*)d_in[6];
  float* out = (float*)d_out;
  unsigned short* wbf = (unsigned short*)d_ws;  // 131072 bytes used

  // arrange weights fp32 -> bf16 frag-linear image (re-done every launch)
  wconvert_kernel<<<W_ELEMS / 256, 256, 0, stream>>>(w_in, w_hid, w_out, wbf);

  // allow >64KB dynamic LDS (gfx950 has 160KB/CU)
  (void)hipFuncSetAttribute((const void*)mlp_kernel,
                            hipFuncAttributeMaxDynamicSharedMemorySize, LDS_BYTES);

  mlp_kernel<<<GRID, BLOCK, LDS_BYTES, stream>>>(x, wbf, b_in, b_hid, b_out, out);
}